// Round 1
// baseline (350.064 us; speedup 1.0000x reference)
//
#include <hip/hip_runtime.h>
#include <hip/hip_bf16.h>
#include <stdint.h>

typedef __attribute__((ext_vector_type(8))) short short8;
typedef __attribute__((ext_vector_type(4))) float f32x4;

#define MFMA16(a, b, c) __builtin_amdgcn_mfma_f32_16x16x32_bf16(a, b, c, 0, 0, 0)

#define D_ 512
#define M_ 16384
#define SREF 2048
#define QT 32
#define KT 64

__device__ __forceinline__ ushort f2bf(float f) {
  union { float f; uint32_t u; } v; v.f = f;
  uint32_t r = v.u + 0x7fffu + ((v.u >> 16) & 1u);
  return (ushort)(r >> 16);
}

__device__ __forceinline__ void gld16(const void* g, void* l) {
  __builtin_amdgcn_global_load_lds(
      (const __attribute__((address_space(1))) void*)g,
      (__attribute__((address_space(3))) void*)l, 16, 0, 0);
}

// ---------------- K1: fused QKV projection -------------------------------
// z=0: Q -> ws[0]        [m][n] bf16
// z=1: K -> ws[M*D]      [m][n] bf16
// z=2: V -> ws[2*M*D]    TRANSPOSED: [b][d][s] bf16
__global__ __launch_bounds__(256) void qkv_kernel(
    const float* __restrict__ X,
    const float* __restrict__ Wq, const float* __restrict__ bq,
    const float* __restrict__ Wk, const float* __restrict__ bk,
    const float* __restrict__ Wv, const float* __restrict__ bv,
    ushort* __restrict__ ws) {
  const int z = blockIdx.z;
  const float* W    = (z == 0) ? Wq : ((z == 1) ? Wk : Wv);
  const float* bias = (z == 0) ? bq : ((z == 1) ? bk : bv);
  ushort* outp = ws + (size_t)z * M_ * D_;

  const int m0 = blockIdx.x * 64;
  const int n0 = blockIdx.y * 64;
  const int tid = threadIdx.x;
  const int lane = tid & 63;
  const int wid = tid >> 6;
  const int lr = lane & 15;
  const int lg = lane >> 4;
  const int m_base = (wid >> 1) * 32;
  const int n_base = (wid & 1) * 32;

  __shared__ __align__(16) ushort At[64][56];
  __shared__ __align__(16) ushort Bt[64][56];

  f32x4 acc[2][2] = {};

  for (int ks = 0; ks < 16; ++ks) {
    const int k0 = ks * 32;
    {  // stage A (X tile) -> bf16
      int r = tid >> 2, c = (tid & 3) * 8;
      const float* px = X + (size_t)(m0 + r) * D_ + k0 + c;
      float4 x0 = *(const float4*)px;
      float4 x1 = *(const float4*)(px + 4);
      uint4 pk;
      pk.x = (uint32_t)f2bf(x0.x) | ((uint32_t)f2bf(x0.y) << 16);
      pk.y = (uint32_t)f2bf(x0.z) | ((uint32_t)f2bf(x0.w) << 16);
      pk.z = (uint32_t)f2bf(x1.x) | ((uint32_t)f2bf(x1.y) << 16);
      pk.w = (uint32_t)f2bf(x1.z) | ((uint32_t)f2bf(x1.w) << 16);
      *(uint4*)&At[r][c] = pk;
    }
    {  // stage B^T (W tile, transposed) -> bf16
      int k = tid >> 3, nn = (tid & 7) * 8;
      const float* pw = W + (size_t)(k0 + k) * D_ + n0 + nn;
      float4 w0 = *(const float4*)pw;
      float4 w1 = *(const float4*)(pw + 4);
      Bt[nn + 0][k] = f2bf(w0.x); Bt[nn + 1][k] = f2bf(w0.y);
      Bt[nn + 2][k] = f2bf(w0.z); Bt[nn + 3][k] = f2bf(w0.w);
      Bt[nn + 4][k] = f2bf(w1.x); Bt[nn + 5][k] = f2bf(w1.y);
      Bt[nn + 6][k] = f2bf(w1.z); Bt[nn + 7][k] = f2bf(w1.w);
    }
    __syncthreads();
    short8 a[2], b[2];
#pragma unroll
    for (int mf = 0; mf < 2; ++mf) a[mf] = *(const short8*)&At[m_base + mf * 16 + lr][lg * 8];
#pragma unroll
    for (int nf = 0; nf < 2; ++nf) b[nf] = *(const short8*)&Bt[n_base + nf * 16 + lr][lg * 8];
#pragma unroll
    for (int mf = 0; mf < 2; ++mf)
#pragma unroll
      for (int nf = 0; nf < 2; ++nf)
        acc[mf][nf] = MFMA16(a[mf], b[nf], acc[mf][nf]);
    __syncthreads();
  }

  const int b_idx = m0 >> 11;
  const int s0 = m0 & 2047;
#pragma unroll
  for (int mf = 0; mf < 2; ++mf) {
#pragma unroll
    for (int nf = 0; nf < 2; ++nf) {
      int n = n0 + n_base + nf * 16 + lr;
      float bv_ = bias[n];
      int mrow = m_base + mf * 16 + lg * 4;
      if (z < 2) {
#pragma unroll
        for (int r = 0; r < 4; ++r)
          outp[(size_t)(m0 + mrow + r) * D_ + n] = f2bf(acc[mf][nf][r] + bv_);
      } else {
        ushort4 st;
        st.x = f2bf(acc[mf][nf][0] + bv_);
        st.y = f2bf(acc[mf][nf][1] + bv_);
        st.z = f2bf(acc[mf][nf][2] + bv_);
        st.w = f2bf(acc[mf][nf][3] + bv_);
        *(ushort4*)&outp[((size_t)b_idx * 512 + n) * 2048 + s0 + mrow] = st;
      }
    }
  }
}

// ---------------- K2: flash attention ------------------------------------
__global__ __launch_bounds__(512) void attn_kernel(
    const ushort* __restrict__ Qg, const ushort* __restrict__ Kg,
    const ushort* __restrict__ Vtg, float* __restrict__ Out) {
  const int b = blockIdx.y;
  const int q0 = blockIdx.x * QT;
  const int tid = threadIdx.x;
  const int lane = tid & 63;
  const int wid = tid >> 6;
  const int lr = lane & 15;
  const int lg = lane >> 4;
  const int mfw = wid >> 2;  // 0..1  (S-tile m-frag of this wave)
  const int nfw = wid & 3;   // 0..3  (S-tile n-frag of this wave)

  // Q: 32 rows x 1024B, XOR-swizzled per row.  KV union:
  //   K view : 64 rows x 1024B swizzled      Vt view: 512 rows x 128B swizzled
  __shared__ __align__(16) ushort Qs[QT * 512];
  __shared__ __align__(16) ushort KVs[512 * 64];
  __shared__ __align__(16) float Ss[QT][68];
  __shared__ __align__(16) ushort Ps[QT][72];
  __shared__ float mstate[QT], lstate[QT], resc[QT];

  const ushort* Qrow = Qg + ((size_t)b * SREF + q0) * 512;
  const ushort* Krow = Kg + (size_t)b * SREF * 512;
  const ushort* Vrow = Vtg + (size_t)b * 512 * 2048;

  // prologue: stage Q (pre-swizzled source so LDS is linear-deposited)
  for (int ii = 0; ii < 4; ++ii) {
    int r = wid * 4 + ii;
    gld16(Qrow + (size_t)r * 512 + (size_t)((lane ^ (r & 7)) * 8), &Qs[r * 512]);
  }
  if (tid < QT) { mstate[tid] = -1e30f; lstate[tid] = 0.0f; }

  f32x4 oacc[2][4] = {};
  __syncthreads();

  for (int kt = 0; kt < SREF / KT; ++kt) {
    const int kv0 = kt * KT;
    // phase A: stage K tile (64 rows)
    for (int ii = 0; ii < 8; ++ii) {
      int r = wid * 8 + ii;
      gld16(Krow + (size_t)(kv0 + r) * 512 + (size_t)((lane ^ (r & 7)) * 8), &KVs[r * 512]);
    }
    __syncthreads();

    // phase B: S = Q K^T (each wave one 16x16 frag of the 32x64 S-tile)
    {
      f32x4 sacc = {0.f, 0.f, 0.f, 0.f};
      const int qrow = mfw * 16 + lr;
      const int krow = nfw * 16 + lr;
      const char* qbase = (const char*)Qs + qrow * 1024;
      const char* kbase = (const char*)KVs + krow * 1024;
      const int qx = (qrow & 7) << 4;
      const int kx = (krow & 7) << 4;
#pragma unroll
      for (int ks = 0; ks < 16; ++ks) {
        short8 a  = *(const short8*)(qbase + (((ks * 64) + lg * 16) ^ qx));
        short8 bb = *(const short8*)(kbase + (((ks * 64) + lg * 16) ^ kx));
        sacc = MFMA16(a, bb, sacc);
      }
#pragma unroll
      for (int r = 0; r < 4; ++r)
        Ss[mfw * 16 + lg * 4 + r][nfw * 16 + lr] = sacc[r];
    }
    __syncthreads();

    // phase C: async-stage V^T tile into KV union + cooperative online softmax
    {
      int rloc = lane >> 3;                   // 0..7  (d-row within 8-row issue)
      int csw = ((lane & 7) ^ rloc) * 8;      // pre-swizzled kv-block
      for (int ii = 0; ii < 8; ++ii) {
        int i = wid * 8 + ii;                 // issue id: d-rows 8i..8i+7
        gld16(Vrow + (size_t)(i * 8 + rloc) * 2048 + kv0 + csw, &KVs[i * 512]);
      }
    }
    {
      int row = tid >> 4, ic = tid & 15;
      float4 sv = *(const float4*)&Ss[row][ic * 4];
      const float scale = 0.04419417382415922f;  // 1/sqrt(512)
      float s0 = sv.x * scale, s1 = sv.y * scale, s2 = sv.z * scale, s3 = sv.w * scale;
      float mx = fmaxf(fmaxf(s0, s1), fmaxf(s2, s3));
#pragma unroll
      for (int off = 1; off < 16; off <<= 1) mx = fmaxf(mx, __shfl_xor(mx, off));
      float mold = mstate[row];
      float mnew = fmaxf(mold, mx);
      float p0 = __expf(s0 - mnew), p1 = __expf(s1 - mnew);
      float p2 = __expf(s2 - mnew), p3 = __expf(s3 - mnew);
      float psum = p0 + p1 + p2 + p3;
#pragma unroll
      for (int off = 1; off < 16; off <<= 1) psum += __shfl_xor(psum, off);
      ushort4 pb;
      pb.x = f2bf(p0); pb.y = f2bf(p1); pb.z = f2bf(p2); pb.w = f2bf(p3);
      *(ushort4*)&Ps[row][ic * 4] = pb;
      if (ic == 0) {
        float sc = __expf(mold - mnew);
        resc[row] = sc;
        mstate[row] = mnew;
        lstate[row] = lstate[row] * sc + psum;
      }
    }
    __syncthreads();

    // phase D: rescale O and accumulate P V   (wave owns d-chunk [wid*64, +64))
#pragma unroll
    for (int mf = 0; mf < 2; ++mf) {
      f32x4 rv;
#pragma unroll
      for (int r = 0; r < 4; ++r) rv[r] = resc[mf * 16 + lg * 4 + r];
#pragma unroll
      for (int nf = 0; nf < 4; ++nf) oacc[mf][nf] *= rv;
    }
#pragma unroll
    for (int kk = 0; kk < 2; ++kk) {
      short8 pA[2];
#pragma unroll
      for (int mf = 0; mf < 2; ++mf)
        pA[mf] = *(const short8*)&Ps[mf * 16 + lr][kk * 32 + lg * 8];
#pragma unroll
      for (int nf = 0; nf < 4; ++nf) {
        int vrow = wid * 64 + nf * 16 + lr;
        const char* vbase = (const char*)KVs + vrow * 128;
        short8 vB = *(const short8*)(vbase + (((kk * 64) + lg * 16) ^ ((vrow & 7) << 4)));
#pragma unroll
        for (int mf = 0; mf < 2; ++mf) oacc[mf][nf] = MFMA16(pA[mf], vB, oacc[mf][nf]);
      }
    }
    __syncthreads();
  }

  // epilogue: O / l
#pragma unroll
  for (int mf = 0; mf < 2; ++mf) {
#pragma unroll
    for (int r = 0; r < 4; ++r) {
      int row = mf * 16 + lg * 4 + r;
      float inv = 1.0f / lstate[row];
      float* op = Out + ((size_t)b * SREF + q0 + row) * 512 + wid * 64;
#pragma unroll
      for (int nf = 0; nf < 4; ++nf) op[nf * 16 + lr] = oacc[mf][nf][r] * inv;
    }
  }
}

extern "C" void kernel_launch(void* const* d_in, const int* in_sizes, int n_in,
                              void* d_out, int out_size, void* d_ws, size_t ws_size,
                              hipStream_t stream) {
  const float* X  = (const float*)d_in[0];
  const float* Wq = (const float*)d_in[1];
  const float* bq = (const float*)d_in[2];
  const float* Wk = (const float*)d_in[3];
  const float* bk = (const float*)d_in[4];
  const float* Wv = (const float*)d_in[5];
  const float* bv = (const float*)d_in[6];
  ushort* ws = (ushort*)d_ws;
  float* out = (float*)d_out;

  dim3 g1(M_ / 64, D_ / 64, 3), b1(256);
  qkv_kernel<<<g1, b1, 0, stream>>>(X, Wq, bq, Wk, bk, Wv, bv, ws);

  dim3 g2(SREF / QT, 8), b2(512);
  attn_kernel<<<g2, b2, 0, stream>>>(ws, ws + (size_t)M_ * D_, ws + 2 * (size_t)M_ * D_, out);
}